// Round 4
// baseline (245.103 us; speedup 1.0000x reference)
//
#include <hip/hip_runtime.h>

typedef __attribute__((ext_vector_type(8)))  short short8;
typedef __attribute__((ext_vector_type(4)))  float f32x4;
typedef __attribute__((ext_vector_type(16))) float f32x16;

constexpr int B  = 2;
constexpr int T  = 2048;
constexpr int C  = 1024;
constexpr int H  = 16;
constexpr int HD = 64;

// ---------------- helpers ----------------
__device__ inline unsigned bf16rne(float a){
  unsigned u = __builtin_bit_cast(unsigned, a);
  u += 0x7fffu + ((u >> 16) & 1u);
  return u >> 16;
}
__device__ inline unsigned bf16pair(float a, float b){
  unsigned ua = __builtin_bit_cast(unsigned, a); ua += 0x7fffu + ((ua >> 16) & 1u);
  unsigned ub = __builtin_bit_cast(unsigned, b); ub += 0x7fffu + ((ub >> 16) & 1u);
  return (ua >> 16) | (ub & 0xffff0000u);
}
__device__ inline void gll16(const void* g, void* l){
  __builtin_amdgcn_global_load_lds(
      (const __attribute__((address_space(1))) unsigned*)g,
      (__attribute__((address_space(3))) unsigned*)l, 16, 0, 0);
}
__device__ inline float exp2f_(float x){
#if __has_builtin(__builtin_amdgcn_exp2f)
  return __builtin_amdgcn_exp2f(x);
#else
  return __builtin_exp2f(x);
#endif
}

// ---------------- fp32 -> bf16 convert: weights + qkv inputs ----------------
__global__ void convert_k(const float* __restrict__ ipw, const float* __restrict__ opw,
                          const float* __restrict__ q, const float* __restrict__ k,
                          const float* __restrict__ v, unsigned* __restrict__ dst)
{
  const int i = blockIdx.x * 256 + threadIdx.x;
  const long e = (long)i * 4;
  const float* src; long off;
  if      (e <  3145728) { src = ipw; off = e; }
  else if (e <  4194304) { src = opw; off = e - 3145728; }
  else if (e <  8388608) { src = q;   off = e - 4194304; }
  else if (e < 12582912) { src = k;   off = e - 8388608; }
  else                   { src = v;   off = e - 12582912; }
  const float4 x = *(const float4*)(src + off);
  dst[i*2+0] = bf16pair(x.x, x.y);
  dst[i*2+1] = bf16pair(x.z, x.w);
}

// ---------------- GEMM: out = A @ W^T + bias ----------------
// 128x128 tile, BK=64 (16 k-steps), 4 waves, 4x4x(2 khalves) of 16x16x32 bf16.
// Grid: x = bn (XCD swizzle: same-bn -> same XCD), y = bm.
// MODE 0: QKV; coalesced LDS-transpose epilogue -> Qb/Kb [b,h,t,d], Vt [b,h,d,t].
// MODE 1: out-proj, fp32 row-major + bias.
template<int MODE>
__global__ __launch_bounds__(256, 2) void gemm_k(
    const unsigned short* __restrict__ A0, const unsigned short* __restrict__ A1,
    const unsigned short* __restrict__ A2,
    const unsigned short* __restrict__ Wb, const float* __restrict__ bias,
    unsigned short* __restrict__ Qb, unsigned short* __restrict__ Kb,
    unsigned short* __restrict__ Vt, float* __restrict__ outF)
{
  __shared__ __align__(16) char gsm[32768];
  unsigned short* As = (unsigned short*)gsm;
  unsigned short* Bs = (unsigned short*)(gsm + 16384);

  const int tid  = threadIdx.x, lane = tid & 63, wv = tid >> 6;
  const int wm   = wv & 1, wn = wv >> 1;
  const int bn   = blockIdx.x, bm = blockIdx.y;
  const int m16  = lane & 15, quad = lane >> 4;

  const int which = (MODE == 0) ? (bn >> 3) : 0;
  const unsigned short* A = (which == 0) ? A0 : (which == 1 ? A1 : A2);

  f32x4 acc[4][4];
#pragma unroll
  for (int i = 0; i < 4; i++)
#pragma unroll
    for (int j = 0; j < 4; j++) acc[i][j] = (f32x4){0.f, 0.f, 0.f, 0.f};

  const int srow = (lane >> 3);        // 0..7 within 8-row chunk
  const int skp  = (lane & 7) * 8;     // k element offset (16B)

  for (int k0 = 0; k0 < 1024; k0 += 64) {
    __syncthreads();
#pragma unroll
    for (int p = 0; p < 4; p++) {
      const int row = wv*32 + p*8 + srow;
      gll16(A  + (size_t)(bm*128 + row)*1024 + k0 + skp, (char*)As + (wv*4+p)*1024);
      gll16(Wb + (size_t)(bn*128 + row)*1024 + k0 + skp, (char*)Bs + (wv*4+p)*1024);
    }
    __syncthreads();

    short8 af[2][4], bf2[2][4];
#pragma unroll
    for (int kh = 0; kh < 2; kh++) {
#pragma unroll
      for (int i = 0; i < 4; i++)
        af[kh][i] = *(const short8*)((const char*)As + (wm*64 + i*16 + m16)*128 + kh*64 + quad*16);
#pragma unroll
      for (int j = 0; j < 4; j++)
        bf2[kh][j] = *(const short8*)((const char*)Bs + (wn*64 + j*16 + m16)*128 + kh*64 + quad*16);
    }
#pragma unroll
    for (int kh = 0; kh < 2; kh++)
#pragma unroll
      for (int i = 0; i < 4; i++)
#pragma unroll
        for (int j = 0; j < 4; j++)
          acc[i][j] = __builtin_amdgcn_mfma_f32_16x16x32_bf16(af[kh][i], bf2[kh][j], acc[i][j], 0,0,0);
  }

  if constexpr (MODE == 1) {
#pragma unroll
    for (int j = 0; j < 4; j++) {
      const int n_e = bn*128 + wn*64 + j*16 + m16;
      const float bj = bias[n_e];
#pragma unroll
      for (int i = 0; i < 4; i++) {
        const int mbase = bm*128 + wm*64 + i*16 + quad*4;
#pragma unroll
        for (int r = 0; r < 4; r++)
          outF[(size_t)(mbase + r) * 1024 + n_e] = acc[i][j][r] + bj;
      }
    }
  } else {
    // coalesced epilogue via LDS transpose
    __syncthreads();
    float* Ls = (float*)gsm;
    const int hbase = (bn & 7) * 2;
    const int b = bm >> 4;
    const int tbase = (bm & 15) * 128;
    if (which < 2) {
      unsigned short* dst = (which == 0 ? Qb : Kb);
#pragma unroll
      for (int j = 0; j < 4; ++j) {
        const float bj = bias[bn*128 + wn*64 + j*16 + m16];
#pragma unroll
        for (int i = 0; i < 4; ++i) {
          const int m0 = wm*64 + i*16 + quad*4;
#pragma unroll
          for (int r = 0; r < 4; ++r)
            Ls[(m0 + r)*36 + wn*16 + m16] = acc[i][j][r] + bj;
        }
        __syncthreads();
#pragma unroll
        for (int r2 = 0; r2 < 2; ++r2) {
          const int v = r2*256 + tid;
          const int m = v & 127, seg = v >> 7;
          const int wn2 = seg >> 1, d0 = j*16 + (seg & 1)*8;
          const float* src = &Ls[m*36 + wn2*16 + (seg & 1)*8];
          const float4 f0 = *(const float4*)src;
          const float4 f1 = *(const float4*)(src + 4);
          uint4 st;
          st.x = bf16pair(f0.x, f0.y); st.y = bf16pair(f0.z, f0.w);
          st.z = bf16pair(f1.x, f1.y); st.w = bf16pair(f1.z, f1.w);
          *(uint4*)&dst[((size_t)((b*16 + hbase + wn2)*2048 + tbase + m))*64 + d0] = st;
        }
        __syncthreads();
      }
    } else {
#pragma unroll
      for (int j = 0; j < 4; ++j) {
        const float bj = bias[bn*128 + wn*64 + j*16 + m16];
        const int col = wn*16 + m16;
#pragma unroll
        for (int i = 0; i < 4; ++i) {
          f32x4 tv = acc[i][j];
          tv[0] += bj; tv[1] += bj; tv[2] += bj; tv[3] += bj;
          *(f32x4*)&Ls[col*132 + wm*64 + i*16 + quad*4] = tv;
        }
        __syncthreads();
#pragma unroll
        for (int r2 = 0; r2 < 2; ++r2) {
          const int v = r2*256 + tid;
          const int n = v >> 4, mseg = v & 15;
          const float* src = &Ls[n*132 + mseg*8];
          const float4 f0 = *(const float4*)src;
          const float4 f1 = *(const float4*)(src + 4);
          uint4 st;
          st.x = bf16pair(f0.x, f0.y); st.y = bf16pair(f0.z, f0.w);
          st.z = bf16pair(f1.x, f1.y); st.w = bf16pair(f1.z, f1.w);
          const int d = j*16 + (n & 15);
          const int hh = hbase + (n >> 4);
          *(uint4*)&Vt[(((size_t)(b*16 + hh))*64 + d)*2048 + tbase + mseg*8] = st;
        }
        __syncthreads();
      }
    }
  }
}

// ---------------- MFMA flash attention, S^T form, reg-prefetch + LDS dbuf ----
// Grid: x = bh (XCD cluster), y = qt. One barrier per kt-step, no gll drain.
__global__ __launch_bounds__(256, 2) void attn_k(
    const unsigned short* __restrict__ Qb, const unsigned short* __restrict__ Kb,
    const unsigned short* __restrict__ Vt, const int* __restrict__ wptr,
    unsigned short* __restrict__ ctx)
{
  __shared__ __align__(16) char smem[33024];  // 2x(Kl 8K + Vl 8K) dbuf; +lbuf
  float* Om   = (float*)smem;                 // epilogue reuse (16 KB)
  float* lbuf = (float*)(smem + 32768);

  const int tid = threadIdx.x, lane = tid & 63, wv = tid >> 6;
  const int wq = wv >> 1, wk = wv & 1;
  const int h = lane >> 5, ln = lane & 31;
  const bool hs = (h == 1);
  const int bh = blockIdx.x, qt = blockIdx.y;
  const int win = *wptr;
  const int q0 = qt * 64 + wq * 32;
  const size_t hb = (size_t)bh * T * HD;

  constexpr float LOG2E = 1.44269504f;
  constexpr float C1    = 0.125f * LOG2E;

  short8 qf[4];
#pragma unroll
  for (int s = 0; s < 4; s++)
    qf[s] = *(const short8*)(Qb + hb + (size_t)(q0 + ln)*64 + s*16 + h*8);

  short8 onesv;
#pragma unroll
  for (int jj = 0; jj < 8; jj++) onesv[jj] = (short)0x3F80;

  f32x16 O0, O1, Lacc, Zv;
#pragma unroll
  for (int r = 0; r < 16; r++) { O0[r] = 0.f; O1[r] = 0.f; Lacc[r] = 0.f; Zv[r] = 0.f; }
  const int tq = q0 + ln;

  // staging geometry: 4 lanes per 64-d row (perfect coalescing)
  const int srow = tid >> 2;            // 0..63
  const int soff = (tid & 3) * 16;      // element offset
  const int c0   = (tid & 3) * 2;       // 1KB chunk index
  const unsigned short* Kg = Kb + hb;
  const unsigned short* Vg = Vt + hb;

  // prologue: tile 0 -> regs -> LDS buf0
  uint4 ka, kb2, va, vb;
  ka  = *(const uint4*)(Kg + (size_t)srow*64 + soff);
  kb2 = *(const uint4*)(Kg + (size_t)srow*64 + soff + 8);
  va  = *(const uint4*)(Vg + (size_t)srow*2048 + soff);
  vb  = *(const uint4*)(Vg + (size_t)srow*2048 + soff + 8);
  {
    char* Kd = smem; char* Vd = smem + 8192;
    *(uint4*)(Kd + c0*1024 + srow*16)     = ka;
    *(uint4*)(Kd + (c0+1)*1024 + srow*16) = kb2;
    *(uint4*)(Vd + c0*1024 + srow*16)     = va;
    *(uint4*)(Vd + (c0+1)*1024 + srow*16) = vb;
  }
  __syncthreads();

  for (int kt = 0; kt < 32; ++kt) {
    // prefetch next tile into regs (no LDS dependency -> no barrier drain)
    if (kt < 31) {
      const int t1 = (kt + 1) * 64;
      ka  = *(const uint4*)(Kg + (size_t)(t1 + srow)*64 + soff);
      kb2 = *(const uint4*)(Kg + (size_t)(t1 + srow)*64 + soff + 8);
      va  = *(const uint4*)(Vg + (size_t)srow*2048 + t1 + soff);
      vb  = *(const uint4*)(Vg + (size_t)srow*2048 + t1 + soff + 8);
    }
    const char* Kl = smem + (kt & 1)*16384;
    const char* Vl = Kl + 8192;

    // S^T = K·Q^T
    f32x16 st;
#pragma unroll
    for (int s = 0; s < 4; s++) {
      const short8 kf = *(const short8*)(Kl + (2*s + h)*1024 + (wk*32 + ln)*16);
      st = __builtin_amdgcn_mfma_f32_32x32x16_bf16(kf, qf[s], (s == 0 ? Zv : st), 0, 0, 0);
    }

    // softmax numerator, exp2 domain, band hoisted when wave-uniform
    const int kb = kt*64 + wk*32;
    int sep = 0;
    if (kb > q0 + 31) sep = kb - (q0 + 31);
    else if (q0 > kb + 31) sep = q0 - (kb + 31);
    const int d1 = kb + 31 - q0, d2 = q0 + 31 - kb;
    const int dmax = max(d1 < 0 ? -d1 : d1, d2 < 0 ? -d2 : d2);

    float pr[16];
    if (sep > win) {
#pragma unroll
      for (int r = 0; r < 16; r++) pr[r] = exp2f_(st[r] * C1);
    } else if (dmax <= win) {
#pragma unroll
      for (int r = 0; r < 16; r++) pr[r] = exp2f_(__builtin_fmaf(st[r], C1, LOG2E));
    } else {
      const int tkb = kb + 4*h;
#pragma unroll
      for (int r = 0; r < 16; r++) {
        const int tk = tkb + (r & 3) + 8*(r >> 2);
        int dd = tq - tk; dd = dd < 0 ? -dd : dd;
        pr[r] = exp2f_(__builtin_fmaf(st[r], C1, dd <= win ? LOG2E : 0.0f));
      }
    }

    unsigned pk[8];
#pragma unroll
    for (int g = 0; g < 8; g++)
      pk[g] = __builtin_amdgcn_perm(__builtin_bit_cast(unsigned, pr[2*g+1]),
                                    __builtin_bit_cast(unsigned, pr[2*g]),
                                    0x07060302u);

#pragma unroll
    for (int c = 0; c < 2; c++) {
      const unsigned sh0 = (unsigned)__shfl_xor((int)pk[4*c+0], 32, 64);
      const unsigned sh1 = (unsigned)__shfl_xor((int)pk[4*c+1], 32, 64);
      const unsigned sh2 = (unsigned)__shfl_xor((int)pk[4*c+2], 32, 64);
      const unsigned sh3 = (unsigned)__shfl_xor((int)pk[4*c+3], 32, 64);
      union { unsigned u[4]; short8 v; } P;
      P.u[0] = hs ? sh2 : pk[4*c+0];
      P.u[1] = hs ? sh3 : pk[4*c+1];
      P.u[2] = hs ? pk[4*c+2] : sh0;
      P.u[3] = hs ? pk[4*c+3] : sh1;
#pragma unroll
      for (int dt = 0; dt < 2; dt++) {
        const short8 vf = *(const short8*)(Vl + (wk*4 + 2*c + h)*1024 + (dt*32 + ln)*16);
        if (dt == 0) O0 = __builtin_amdgcn_mfma_f32_32x32x16_bf16(P.v, vf, O0, 0,0,0);
        else         O1 = __builtin_amdgcn_mfma_f32_32x32x16_bf16(P.v, vf, O1, 0,0,0);
      }
      Lacc = __builtin_amdgcn_mfma_f32_32x32x16_bf16(P.v, onesv, Lacc, 0,0,0);
    }

    // stage prefetched regs into the other buffer; single barrier per step
    if (kt < 31) {
      char* Kd = smem + ((kt + 1) & 1)*16384;
      char* Vd = Kd + 8192;
      *(uint4*)(Kd + c0*1024 + srow*16)     = ka;
      *(uint4*)(Kd + (c0+1)*1024 + srow*16) = kb2;
      *(uint4*)(Vd + c0*1024 + srow*16)     = va;
      *(uint4*)(Vd + (c0+1)*1024 + srow*16) = vb;
      __syncthreads();
    }
  }

  __syncthreads();
  if (wk == 1) {
#pragma unroll
    for (int r = 0; r < 16; r++) {
      Om[wq*2048 + r*64 + lane]        = O0[r];
      Om[wq*2048 + (16 + r)*64 + lane] = O1[r];
    }
    if (ln == 0) {
#pragma unroll
      for (int r = 0; r < 16; r++)
        lbuf[wq*32 + (r & 3) + 8*(r >> 2) + 4*h] = Lacc[r];
    }
  }
  __syncthreads();
  if (wk == 0) {
    const int b = bh >> 4, hh = bh & 15;
#pragma unroll
    for (int r = 0; r < 16; r++) {
      const int qrow = (r & 3) + 8*(r >> 2) + 4*h;
      const float lt = Lacc[r] + lbuf[wq*32 + qrow];
      const float linv = 1.0f / lt;
      const int t = q0 + qrow;
      const float o0 = (O0[r] + Om[wq*2048 + r*64 + lane]) * linv;
      const float o1 = (O1[r] + Om[wq*2048 + (16 + r)*64 + lane]) * linv;
      unsigned short* cp = ctx + (size_t)(b*2048 + t)*1024 + hh*64;
      cp[ln]      = (unsigned short)bf16rne(o0);
      cp[32 + ln] = (unsigned short)bf16rne(o1);
    }
  }
}

// ---------------- launch ----------------
extern "C" void kernel_launch(void* const* d_in, const int* in_sizes, int n_in,
                              void* d_out, int out_size, void* d_ws, size_t ws_size,
                              hipStream_t stream)
{
  const float* query = (const float*)d_in[0];
  const float* key   = (const float*)d_in[1];
  const float* value = (const float*)d_in[2];
  const float* ipw   = (const float*)d_in[3];
  const float* ipb   = (const float*)d_in[4];
  const float* opw   = (const float*)d_in[5];
  const float* opb   = (const float*)d_in[6];
  const int*   win   = (const int*)d_in[7];

  char* ws = (char*)d_ws;
  unsigned short* Winbf  = (unsigned short*)(ws);             // 3072*1024
  unsigned short* Woutbf = (unsigned short*)(ws + 6291456);   // 1024*1024
  unsigned short* Qin    = (unsigned short*)(ws + 8388608);   // [4096,1024] bf16
  unsigned short* Kin    = (unsigned short*)(ws + 16777216);
  unsigned short* Vin    = (unsigned short*)(ws + 25165824);
  unsigned short* Qb     = (unsigned short*)(ws + 33554432);  // [b,h,t,d]
  unsigned short* Kb     = (unsigned short*)(ws + 41943040);  // [b,h,t,d]
  unsigned short* Vt     = (unsigned short*)(ws + 50331648);  // [b,h,d,t]
  unsigned short* ctx    = (unsigned short*)(ws + 58720256);  // [4096][1024]

  convert_k<<<16384, 256, 0, stream>>>(ipw, opw, query, key, value, (unsigned*)ws);

  gemm_k<0><<<dim3(24, 32), 256, 0, stream>>>(
      Qin, Kin, Vin, Winbf, ipb, Qb, Kb, Vt, nullptr);

  attn_k<<<dim3(32, 32), 256, 0, stream>>>(Qb, Kb, Vt, win, ctx);

  gemm_k<1><<<dim3(8, 32), 256, 0, stream>>>(
      ctx, ctx, ctx, Woutbf, opb, nullptr, nullptr, nullptr, (float*)d_out);
}

// Round 5
// 229.809 us; speedup vs baseline: 1.0666x; 1.0666x over previous
//
#include <hip/hip_runtime.h>

typedef __attribute__((ext_vector_type(8)))  short short8;
typedef __attribute__((ext_vector_type(4)))  float f32x4;
typedef __attribute__((ext_vector_type(16))) float f32x16;

constexpr int B  = 2;
constexpr int T  = 2048;
constexpr int C  = 1024;
constexpr int H  = 16;
constexpr int HD = 64;

// ---------------- helpers ----------------
__device__ inline unsigned bf16rne(float a){
  unsigned u = __builtin_bit_cast(unsigned, a);
  u += 0x7fffu + ((u >> 16) & 1u);
  return u >> 16;
}
__device__ inline unsigned bf16pair(float a, float b){
  unsigned ua = __builtin_bit_cast(unsigned, a); ua += 0x7fffu + ((ua >> 16) & 1u);
  unsigned ub = __builtin_bit_cast(unsigned, b); ub += 0x7fffu + ((ub >> 16) & 1u);
  return (ua >> 16) | (ub & 0xffff0000u);
}
__device__ inline void gll16(const void* g, void* l){
  __builtin_amdgcn_global_load_lds(
      (const __attribute__((address_space(1))) unsigned*)g,
      (__attribute__((address_space(3))) unsigned*)l, 16, 0, 0);
}
__device__ inline float exp2f_(float x){
#if __has_builtin(__builtin_amdgcn_exp2f)
  return __builtin_amdgcn_exp2f(x);
#else
  return __builtin_exp2f(x);
#endif
}

// ---------------- fp32 -> bf16 convert: weights + qkv inputs ----------------
__global__ void convert_k(const float* __restrict__ ipw, const float* __restrict__ opw,
                          const float* __restrict__ q, const float* __restrict__ k,
                          const float* __restrict__ v, unsigned* __restrict__ dst)
{
  const int i = blockIdx.x * 256 + threadIdx.x;
  const long e = (long)i * 4;
  const float* src; long off;
  if      (e <  3145728) { src = ipw; off = e; }
  else if (e <  4194304) { src = opw; off = e - 3145728; }
  else if (e <  8388608) { src = q;   off = e - 4194304; }
  else if (e < 12582912) { src = k;   off = e - 8388608; }
  else                   { src = v;   off = e - 12582912; }
  const float4 x = *(const float4*)(src + off);
  dst[i*2+0] = bf16pair(x.x, x.y);
  dst[i*2+1] = bf16pair(x.z, x.w);
}

// ---------------- GEMM: out = A @ W^T + bias ----------------
// 128x128 tile, BK=64, 4 waves, 4x4x2 of 16x16x32 bf16, gll staging.
// MODE 0: QKV. Epilogue: Q -> [b,h,t,d]; K -> fragment-major Kf; V -> Vf.
// MODE 1: out-proj, fp32 row-major + bias.
template<int MODE>
__global__ __launch_bounds__(256, 2) void gemm_k(
    const unsigned short* __restrict__ A0, const unsigned short* __restrict__ A1,
    const unsigned short* __restrict__ A2,
    const unsigned short* __restrict__ Wb, const float* __restrict__ bias,
    unsigned short* __restrict__ Qb, unsigned short* __restrict__ Kf,
    unsigned short* __restrict__ Vf, float* __restrict__ outF)
{
  __shared__ __align__(16) char gsm[32768];
  unsigned short* As = (unsigned short*)gsm;
  unsigned short* Bs = (unsigned short*)(gsm + 16384);

  const int tid  = threadIdx.x, lane = tid & 63, wv = tid >> 6;
  const int wm   = wv & 1, wn = wv >> 1;
  const int bn   = blockIdx.x, bm = blockIdx.y;
  const int m16  = lane & 15, quad = lane >> 4;

  const int which = (MODE == 0) ? (bn >> 3) : 0;
  const unsigned short* A = (which == 0) ? A0 : (which == 1 ? A1 : A2);

  f32x4 acc[4][4];
#pragma unroll
  for (int i = 0; i < 4; i++)
#pragma unroll
    for (int j = 0; j < 4; j++) acc[i][j] = (f32x4){0.f, 0.f, 0.f, 0.f};

  const int srow = (lane >> 3);
  const int skp  = (lane & 7) * 8;

  for (int k0 = 0; k0 < 1024; k0 += 64) {
    __syncthreads();
#pragma unroll
    for (int p = 0; p < 4; p++) {
      const int row = wv*32 + p*8 + srow;
      gll16(A  + (size_t)(bm*128 + row)*1024 + k0 + skp, (char*)As + (wv*4+p)*1024);
      gll16(Wb + (size_t)(bn*128 + row)*1024 + k0 + skp, (char*)Bs + (wv*4+p)*1024);
    }
    __syncthreads();

    short8 af[2][4], bf2[2][4];
#pragma unroll
    for (int kh = 0; kh < 2; kh++) {
#pragma unroll
      for (int i = 0; i < 4; i++)
        af[kh][i] = *(const short8*)((const char*)As + (wm*64 + i*16 + m16)*128 + kh*64 + quad*16);
#pragma unroll
      for (int j = 0; j < 4; j++)
        bf2[kh][j] = *(const short8*)((const char*)Bs + (wn*64 + j*16 + m16)*128 + kh*64 + quad*16);
    }
#pragma unroll
    for (int kh = 0; kh < 2; kh++)
#pragma unroll
      for (int i = 0; i < 4; i++)
#pragma unroll
        for (int j = 0; j < 4; j++)
          acc[i][j] = __builtin_amdgcn_mfma_f32_16x16x32_bf16(af[kh][i], bf2[kh][j], acc[i][j], 0,0,0);
  }

  if constexpr (MODE == 1) {
#pragma unroll
    for (int j = 0; j < 4; j++) {
      const int n_e = bn*128 + wn*64 + j*16 + m16;
      const float bj = bias[n_e];
#pragma unroll
      for (int i = 0; i < 4; i++) {
        const int mbase = bm*128 + wm*64 + i*16 + quad*4;
#pragma unroll
        for (int r = 0; r < 4; r++)
          outF[(size_t)(mbase + r) * 1024 + n_e] = acc[i][j][r] + bj;
      }
    }
  } else {
    __syncthreads();
    float* Ls = (float*)gsm;
    const int hbase = (bn & 7) * 2;
    const int b = bm >> 4;
    const int tbase = (bm & 15) * 128;
    if (which < 2) {
#pragma unroll
      for (int j = 0; j < 4; ++j) {
        const float bj = bias[bn*128 + wn*64 + j*16 + m16];
#pragma unroll
        for (int i = 0; i < 4; ++i) {
          const int m0 = wm*64 + i*16 + quad*4;
#pragma unroll
          for (int r = 0; r < 4; ++r)
            Ls[(m0 + r)*36 + wn*16 + m16] = acc[i][j][r] + bj;
        }
        __syncthreads();
#pragma unroll
        for (int r2 = 0; r2 < 2; ++r2) {
          const int v = r2*256 + tid;
          const int m = v & 127, seg = v >> 7;
          const int wn2 = seg >> 1;
          const float* src = &Ls[m*36 + wn2*16 + (seg & 1)*8];
          const float4 f0 = *(const float4*)src;
          const float4 f1 = *(const float4*)(src + 4);
          uint4 st;
          st.x = bf16pair(f0.x, f0.y); st.y = bf16pair(f0.z, f0.w);
          st.z = bf16pair(f1.x, f1.y); st.w = bf16pair(f1.z, f1.w);
          const int bhh = b*16 + hbase + wn2;
          if (which == 0) {
            const int d0 = j*16 + (seg & 1)*8;
            *(uint4*)&Qb[((size_t)(bhh*2048) + tbase + m)*64 + d0] = st;
          } else {
            // K fragment-major: cell = ((bh*32+kt)*8 + s*2 + wk), lane = h2*32+ln
            const int kt = (tbase + m) >> 6;
            const int wkk = (m >> 5) & 1, ln2 = m & 31;
            const int h2 = seg & 1;                // s = j
            uint4* dp = (uint4*)Kf + ((size_t)(bhh*32 + kt)*8 + j*2 + wkk)*64 + h2*32 + ln2;
            *dp = st;
          }
        }
        __syncthreads();
      }
    } else {
#pragma unroll
      for (int j = 0; j < 4; ++j) {
        const float bj = bias[bn*128 + wn*64 + j*16 + m16];
        const int col = wn*16 + m16;
#pragma unroll
        for (int i = 0; i < 4; ++i) {
          f32x4 tv = acc[i][j];
          tv[0] += bj; tv[1] += bj; tv[2] += bj; tv[3] += bj;
          *(f32x4*)&Ls[col*132 + wm*64 + i*16 + quad*4] = tv;
        }
        __syncthreads();
#pragma unroll
        for (int r2 = 0; r2 < 2; ++r2) {
          const int v = r2*256 + tid;
          const int n = v >> 4, mseg = v & 15;
          const float* src = &Ls[n*132 + mseg*8];
          const float4 f0 = *(const float4*)src;
          const float4 f1 = *(const float4*)(src + 4);
          uint4 st;
          st.x = bf16pair(f0.x, f0.y); st.y = bf16pair(f0.z, f0.w);
          st.z = bf16pair(f1.x, f1.y); st.w = bf16pair(f1.z, f1.w);
          const int d = j*16 + (n & 15);
          const int bhh = b*16 + hbase + (n >> 4);
          const int t0 = tbase + mseg*8;
          // V fragment-major: cell = (((bh*32+kt)*2+dt)*2+c)*2+wk, lane = h2*32+ln
          const int kt = t0 >> 6, tc = (t0 & 63) >> 3;
          const int wkk = tc >> 2, cc = (tc >> 1) & 1, h2 = tc & 1;
          const int dt = d >> 5, ln2 = d & 31;
          uint4* dp = (uint4*)Vf + (size_t)(bhh*32 + kt)*512 + dt*256 + cc*128 + wkk*64 + h2*32 + ln2;
          *dp = st;
        }
        __syncthreads();
      }
    }
  }
}

// ---------------- MFMA flash attention: barrier-free, LDS-free K-loop -------
// K/V read directly as fragments from Kf/Vf (coalesced 16B/lane), register
// ping-pong prefetch 1 tile ahead. Grid: x = bh (XCD cluster), y = qt.
__global__ __launch_bounds__(256, 2) void attn_k(
    const unsigned short* __restrict__ Qb, const unsigned short* __restrict__ Kf,
    const unsigned short* __restrict__ Vf, const int* __restrict__ wptr,
    unsigned short* __restrict__ ctx)
{
  __shared__ __align__(16) char smem[16896];
  float* Om   = (float*)smem;          // 16 KB epilogue exchange
  float* lbuf = (float*)(smem + 16384);

  const int tid = threadIdx.x, lane = tid & 63, wv = tid >> 6;
  const int wq = wv >> 1, wk = wv & 1;
  const int h = lane >> 5, ln = lane & 31;
  const bool hs = (h == 1);
  const int bh = blockIdx.x, qt = blockIdx.y;
  const int win = *wptr;
  const int q0 = qt * 64 + wq * 32;
  const size_t hb = (size_t)bh * T * HD;

  constexpr float LOG2E = 1.44269504f;
  constexpr float C1    = 0.125f * LOG2E;

  short8 qf[4];
#pragma unroll
  for (int s = 0; s < 4; s++)
    qf[s] = *(const short8*)(Qb + hb + (size_t)(q0 + ln)*64 + s*16 + h*8);

  short8 onesv;
#pragma unroll
  for (int jj = 0; jj < 8; jj++) onesv[jj] = (short)0x3F80;

  f32x16 O0, O1, Lacc, Zv;
#pragma unroll
  for (int r = 0; r < 16; r++) { O0[r] = 0.f; O1[r] = 0.f; Lacc[r] = 0.f; Zv[r] = 0.f; }
  const int tq = q0 + ln;

  // fragment bases (16B units). Per kt: 512 uint4 cells in both Kf and Vf.
  const uint4* kbase = (const uint4*)Kf + (size_t)bh*32*512 + wk*64 + lane;
  const uint4* vbase = (const uint4*)Vf + (size_t)bh*32*512 + wk*64 + lane;

  uint4 kA[4], vA[4], kB[4], vB[4];
#pragma unroll
  for (int s = 0; s < 4; s++) kA[s] = kbase[s*128];
#pragma unroll
  for (int u = 0; u < 4; u++) vA[u] = vbase[(u >> 1)*256 + (u & 1)*128];  // u = dt*2+c

  auto body = [&](int kt, uint4 (&ka)[4], uint4 (&va)[4]) {
    // S^T = K·Q^T
    f32x16 st;
#pragma unroll
    for (int s = 0; s < 4; s++) {
      const short8 kf2 = __builtin_bit_cast(short8, ka[s]);
      st = __builtin_amdgcn_mfma_f32_32x32x16_bf16(kf2, qf[s], (s == 0 ? Zv : st), 0, 0, 0);
    }

    const int kb = kt*64 + wk*32;
    int sep = 0;
    if (kb > q0 + 31) sep = kb - (q0 + 31);
    else if (q0 > kb + 31) sep = q0 - (kb + 31);
    const int d1 = kb + 31 - q0, d2 = q0 + 31 - kb;
    const int dmax = max(d1 < 0 ? -d1 : d1, d2 < 0 ? -d2 : d2);

    float pr[16];
    if (sep > win) {
#pragma unroll
      for (int r = 0; r < 16; r++) pr[r] = exp2f_(st[r] * C1);
    } else if (dmax <= win) {
#pragma unroll
      for (int r = 0; r < 16; r++) pr[r] = exp2f_(__builtin_fmaf(st[r], C1, LOG2E));
    } else {
      const int tkb = kb + 4*h;
#pragma unroll
      for (int r = 0; r < 16; r++) {
        const int tk = tkb + (r & 3) + 8*(r >> 2);
        int dd = tq - tk; dd = dd < 0 ? -dd : dd;
        pr[r] = exp2f_(__builtin_fmaf(st[r], C1, dd <= win ? LOG2E : 0.0f));
      }
    }

    unsigned pk[8];
#pragma unroll
    for (int g = 0; g < 8; g++)
      pk[g] = __builtin_amdgcn_perm(__builtin_bit_cast(unsigned, pr[2*g+1]),
                                    __builtin_bit_cast(unsigned, pr[2*g]),
                                    0x07060302u);

#pragma unroll
    for (int c = 0; c < 2; c++) {
      const unsigned sh0 = (unsigned)__shfl_xor((int)pk[4*c+0], 32, 64);
      const unsigned sh1 = (unsigned)__shfl_xor((int)pk[4*c+1], 32, 64);
      const unsigned sh2 = (unsigned)__shfl_xor((int)pk[4*c+2], 32, 64);
      const unsigned sh3 = (unsigned)__shfl_xor((int)pk[4*c+3], 32, 64);
      union { unsigned u[4]; short8 v; } P;
      P.u[0] = hs ? sh2 : pk[4*c+0];
      P.u[1] = hs ? sh3 : pk[4*c+1];
      P.u[2] = hs ? pk[4*c+2] : sh0;
      P.u[3] = hs ? pk[4*c+3] : sh1;
#pragma unroll
      for (int dt = 0; dt < 2; dt++) {
        const short8 vf2 = __builtin_bit_cast(short8, va[dt*2 + c]);
        if (dt == 0) O0 = __builtin_amdgcn_mfma_f32_32x32x16_bf16(P.v, vf2, O0, 0,0,0);
        else         O1 = __builtin_amdgcn_mfma_f32_32x32x16_bf16(P.v, vf2, O1, 0,0,0);
      }
      Lacc = __builtin_amdgcn_mfma_f32_32x32x16_bf16(P.v, onesv, Lacc, 0,0,0);
    }
  };

  for (int kt = 0; kt < 32; kt += 2) {
    {
      const size_t o = (size_t)(kt + 1) * 512;
#pragma unroll
      for (int s = 0; s < 4; s++) kB[s] = kbase[o + s*128];
#pragma unroll
      for (int u = 0; u < 4; u++) vB[u] = vbase[o + (u >> 1)*256 + (u & 1)*128];
    }
    body(kt, kA, vA);
    if (kt + 2 < 32) {
      const size_t o = (size_t)(kt + 2) * 512;
#pragma unroll
      for (int s = 0; s < 4; s++) kA[s] = kbase[o + s*128];
#pragma unroll
      for (int u = 0; u < 4; u++) vA[u] = vbase[o + (u >> 1)*256 + (u & 1)*128];
    }
    body(kt + 1, kB, vB);
  }

  __syncthreads();
  if (wk == 1) {
#pragma unroll
    for (int r = 0; r < 16; r++) {
      Om[wq*2048 + r*64 + lane]        = O0[r];
      Om[wq*2048 + (16 + r)*64 + lane] = O1[r];
    }
    if (ln == 0) {
#pragma unroll
      for (int r = 0; r < 16; r++)
        lbuf[wq*32 + (r & 3) + 8*(r >> 2) + 4*h] = Lacc[r];
    }
  }
  __syncthreads();
  if (wk == 0) {
    const int b = bh >> 4, hh = bh & 15;
#pragma unroll
    for (int r = 0; r < 16; r++) {
      const int qrow = (r & 3) + 8*(r >> 2) + 4*h;
      const float lt = Lacc[r] + lbuf[wq*32 + qrow];
      const float linv = 1.0f / lt;
      const int t = q0 + qrow;
      const float o0 = (O0[r] + Om[wq*2048 + r*64 + lane]) * linv;
      const float o1 = (O1[r] + Om[wq*2048 + (16 + r)*64 + lane]) * linv;
      unsigned short* cp = ctx + (size_t)(b*2048 + t)*1024 + hh*64;
      cp[ln]      = (unsigned short)bf16rne(o0);
      cp[32 + ln] = (unsigned short)bf16rne(o1);
    }
  }
}

// ---------------- launch ----------------
extern "C" void kernel_launch(void* const* d_in, const int* in_sizes, int n_in,
                              void* d_out, int out_size, void* d_ws, size_t ws_size,
                              hipStream_t stream)
{
  const float* query = (const float*)d_in[0];
  const float* key   = (const float*)d_in[1];
  const float* value = (const float*)d_in[2];
  const float* ipw   = (const float*)d_in[3];
  const float* ipb   = (const float*)d_in[4];
  const float* opw   = (const float*)d_in[5];
  const float* opb   = (const float*)d_in[6];
  const int*   win   = (const int*)d_in[7];

  char* ws = (char*)d_ws;
  unsigned short* Winbf  = (unsigned short*)(ws);             // 3072*1024
  unsigned short* Woutbf = (unsigned short*)(ws + 6291456);   // 1024*1024
  unsigned short* Qin    = (unsigned short*)(ws + 8388608);   // [4096,1024] bf16
  unsigned short* Kin    = (unsigned short*)(ws + 16777216);
  unsigned short* Vin    = (unsigned short*)(ws + 25165824);
  unsigned short* Qb     = (unsigned short*)(ws + 33554432);  // [b,h,t,d]
  unsigned short* Kf     = (unsigned short*)(ws + 41943040);  // fragment-major
  unsigned short* Vf     = (unsigned short*)(ws + 50331648);  // fragment-major
  unsigned short* ctx    = (unsigned short*)(ws + 58720256);  // [4096][1024]

  convert_k<<<16384, 256, 0, stream>>>(ipw, opw, query, key, value, (unsigned*)ws);

  gemm_k<0><<<dim3(24, 32), 256, 0, stream>>>(
      Qin, Kin, Vin, Winbf, ipb, Qb, Kf, Vf, nullptr);

  attn_k<<<dim3(32, 32), 256, 0, stream>>>(Qb, Kf, Vf, win, ctx);

  gemm_k<1><<<dim3(8, 32), 256, 0, stream>>>(
      ctx, ctx, ctx, Woutbf, opb, nullptr, nullptr, nullptr, (float*)d_out);
}

// Round 6
// 226.237 us; speedup vs baseline: 1.0834x; 1.0158x over previous
//
#include <hip/hip_runtime.h>

typedef __attribute__((ext_vector_type(8)))  short short8;
typedef __attribute__((ext_vector_type(4)))  float f32x4;
typedef __attribute__((ext_vector_type(16))) float f32x16;

constexpr int B  = 2;
constexpr int T  = 2048;
constexpr int C  = 1024;
constexpr int H  = 16;
constexpr int HD = 64;

// ---------------- helpers ----------------
__device__ inline unsigned bf16rne(float a){
  unsigned u = __builtin_bit_cast(unsigned, a);
  u += 0x7fffu + ((u >> 16) & 1u);
  return u >> 16;
}
__device__ inline unsigned bf16pair(float a, float b){
  unsigned ua = __builtin_bit_cast(unsigned, a); ua += 0x7fffu + ((ua >> 16) & 1u);
  unsigned ub = __builtin_bit_cast(unsigned, b); ub += 0x7fffu + ((ub >> 16) & 1u);
  return (ua >> 16) | (ub & 0xffff0000u);
}
__device__ inline void gll16(const void* g, void* l){
  __builtin_amdgcn_global_load_lds(
      (const __attribute__((address_space(1))) unsigned*)g,
      (__attribute__((address_space(3))) unsigned*)l, 16, 0, 0);
}
__device__ inline float exp2f_(float x){
#if __has_builtin(__builtin_amdgcn_exp2f)
  return __builtin_amdgcn_exp2f(x);
#else
  return __builtin_exp2f(x);
#endif
}

// ---------------- fp32 -> bf16 convert: weights + qkv inputs ----------------
__global__ void convert_k(const float* __restrict__ ipw, const float* __restrict__ opw,
                          const float* __restrict__ q, const float* __restrict__ k,
                          const float* __restrict__ v, unsigned* __restrict__ dst)
{
  const int i = blockIdx.x * 256 + threadIdx.x;
  const long e = (long)i * 4;
  const float* src; long off;
  if      (e <  3145728) { src = ipw; off = e; }
  else if (e <  4194304) { src = opw; off = e - 3145728; }
  else if (e <  8388608) { src = q;   off = e - 4194304; }
  else if (e < 12582912) { src = k;   off = e - 8388608; }
  else                   { src = v;   off = e - 12582912; }
  const float4 x = *(const float4*)(src + off);
  dst[i*2+0] = bf16pair(x.x, x.y);
  dst[i*2+1] = bf16pair(x.z, x.w);
}

// ---------------- QKV GEMM: m97-exact BK=32, 128x128, 16 MFMA/step ----------
// Epilogue: Q -> [b,h,t,d]; K -> fragment-major Kf, PRE-SCALED by 0.125*log2e;
// V -> fragment-major Vf.
__global__ __launch_bounds__(256, 3) void gemm_qkv(
    const unsigned short* __restrict__ A0, const unsigned short* __restrict__ A1,
    const unsigned short* __restrict__ A2,
    const unsigned short* __restrict__ Wb, const float* __restrict__ bias,
    unsigned short* __restrict__ Qb, unsigned short* __restrict__ Kf,
    unsigned short* __restrict__ Vf)
{
  __shared__ __align__(16) char gsm[18944];   // K-loop: As 8K + Bs 8K; epi: Ls 18.4K
  unsigned short* As = (unsigned short*)gsm;
  unsigned short* Bs = (unsigned short*)(gsm + 8192);

  const int tid  = threadIdx.x, lane = tid & 63, wv = tid >> 6;
  const int wm   = wv & 1, wn = wv >> 1;
  const int bn   = blockIdx.x, bm = blockIdx.y;
  const int m16  = lane & 15, quad = lane >> 4;

  const int which = bn >> 3;
  const unsigned short* A = (which == 0) ? A0 : (which == 1 ? A1 : A2);

  f32x4 acc[4][4];
#pragma unroll
  for (int i = 0; i < 4; i++)
#pragma unroll
    for (int j = 0; j < 4; j++) acc[i][j] = (f32x4){0.f, 0.f, 0.f, 0.f};

  const int srow = wv * 32 + (lane >> 2);   // +16 for p=1
  const int skp  = (lane & 3) * 8;

  for (int k0 = 0; k0 < 1024; k0 += 32) {
    __syncthreads();
#pragma unroll
    for (int p = 0; p < 2; p++) {
      gll16(A  + (size_t)(bm*128 + srow + p*16)*1024 + k0 + skp, (char*)As + wv*2048 + p*1024);
      gll16(Wb + (size_t)(bn*128 + srow + p*16)*1024 + k0 + skp, (char*)Bs + wv*2048 + p*1024);
    }
    __syncthreads();

    short8 af[4], bf[4];
#pragma unroll
    for (int i = 0; i < 4; i++)
      af[i] = *(const short8*)((const char*)As + (wm*64 + i*16 + m16)*64 + quad*16);
#pragma unroll
    for (int j = 0; j < 4; j++)
      bf[j] = *(const short8*)((const char*)Bs + (wn*64 + j*16 + m16)*64 + quad*16);
#pragma unroll
    for (int i = 0; i < 4; i++)
#pragma unroll
      for (int j = 0; j < 4; j++)
        acc[i][j] = __builtin_amdgcn_mfma_f32_16x16x32_bf16(af[i], bf[j], acc[i][j], 0,0,0);
  }

  __syncthreads();
  float* Ls = (float*)gsm;
  const int hbase = (bn & 7) * 2;
  const int b = bm >> 4;
  const int tbase = (bm & 15) * 128;
  const float ksc = (which == 1) ? 0.18033688f : 1.0f;   // 0.125 * log2(e)

  if (which < 2) {
#pragma unroll
    for (int j = 0; j < 4; ++j) {
      const float bj = bias[bn*128 + wn*64 + j*16 + m16] * ksc;
#pragma unroll
      for (int i = 0; i < 4; ++i) {
        const int m0 = wm*64 + i*16 + quad*4;
#pragma unroll
        for (int r = 0; r < 4; ++r)
          Ls[(m0 + r)*36 + wn*16 + m16] = __builtin_fmaf(acc[i][j][r], ksc, bj);
      }
      __syncthreads();
#pragma unroll
      for (int r2 = 0; r2 < 2; ++r2) {
        const int v = r2*256 + tid;
        const int m = v & 127, seg = v >> 7;
        const int wn2 = seg >> 1;
        const float* src = &Ls[m*36 + wn2*16 + (seg & 1)*8];
        const float4 f0 = *(const float4*)src;
        const float4 f1 = *(const float4*)(src + 4);
        uint4 st;
        st.x = bf16pair(f0.x, f0.y); st.y = bf16pair(f0.z, f0.w);
        st.z = bf16pair(f1.x, f1.y); st.w = bf16pair(f1.z, f1.w);
        const int bhh = b*16 + hbase + wn2;
        if (which == 0) {
          const int d0 = j*16 + (seg & 1)*8;
          *(uint4*)&Qb[((size_t)(bhh*2048) + tbase + m)*64 + d0] = st;
        } else {
          // K fragment-major: cell = ((bh*32+kt)*8 + s*2 + wk)*64 + h2*32 + ln
          const int kt = (tbase + m) >> 6;
          const int wkk = (m >> 5) & 1, ln2 = m & 31;
          const int h2 = seg & 1;               // s = j
          uint4* dp = (uint4*)Kf + ((size_t)(bhh*32 + kt)*8 + j*2 + wkk)*64 + h2*32 + ln2;
          *dp = st;
        }
      }
      __syncthreads();
    }
  } else {
#pragma unroll
    for (int j = 0; j < 4; ++j) {
      const float bj = bias[bn*128 + wn*64 + j*16 + m16];
      const int col = wn*16 + m16;
#pragma unroll
      for (int i = 0; i < 4; ++i) {
        f32x4 tv = acc[i][j];
        tv[0] += bj; tv[1] += bj; tv[2] += bj; tv[3] += bj;
        *(f32x4*)&Ls[col*132 + wm*64 + i*16 + quad*4] = tv;
      }
      __syncthreads();
#pragma unroll
      for (int r2 = 0; r2 < 2; ++r2) {
        const int v = r2*256 + tid;
        const int n = v >> 4, mseg = v & 15;
        const float* src = &Ls[n*132 + mseg*8];
        const float4 f0 = *(const float4*)src;
        const float4 f1 = *(const float4*)(src + 4);
        uint4 st;
        st.x = bf16pair(f0.x, f0.y); st.y = bf16pair(f0.z, f0.w);
        st.z = bf16pair(f1.x, f1.y); st.w = bf16pair(f1.z, f1.w);
        const int d = j*16 + (n & 15);
        const int bhh = b*16 + hbase + (n >> 4);
        const int t0 = tbase + mseg*8;
        // V fragment-major: cell = (((bh*32+kt)*2+dt)*2+c)*2+wk
        const int kt = t0 >> 6, tc = (t0 & 63) >> 3;
        const int wkk = tc >> 2, cc = (tc >> 1) & 1, h2 = tc & 1;
        const int dt = d >> 5, ln2 = d & 31;
        uint4* dp = (uint4*)Vf + (size_t)(bhh*32 + kt)*512 + dt*256 + cc*128 + wkk*64 + h2*32 + ln2;
        *dp = st;
      }
      __syncthreads();
    }
  }
}

// ---------------- out-proj GEMM: 128x64 tile, BK=32, 512 blocks (2/CU) -------
__global__ __launch_bounds__(256, 3) void gemm_out(
    const unsigned short* __restrict__ Ab, const unsigned short* __restrict__ Wb,
    const float* __restrict__ bias, float* __restrict__ outF)
{
  __shared__ __align__(16) char gsm[12288];
  unsigned short* As = (unsigned short*)gsm;          // [128][32]
  unsigned short* Ws = (unsigned short*)(gsm + 8192); // [64][32]

  const int tid  = threadIdx.x, lane = tid & 63, wv = tid >> 6;
  const int wm   = wv & 1, wn = wv >> 1;
  const int bn   = blockIdx.x, bm = blockIdx.y;       // bn: 16, bm: 32
  const int m16  = lane & 15, quad = lane >> 4;

  f32x4 acc[4][2];
#pragma unroll
  for (int i = 0; i < 4; i++)
#pragma unroll
    for (int j = 0; j < 2; j++) acc[i][j] = (f32x4){0.f, 0.f, 0.f, 0.f};

  const int arow = wv * 32 + (lane >> 2);   // +16 for p=1
  const int wrow = wv * 16 + (lane >> 2);
  const int skp  = (lane & 3) * 8;

  for (int k0 = 0; k0 < 1024; k0 += 32) {
    __syncthreads();
#pragma unroll
    for (int p = 0; p < 2; p++)
      gll16(Ab + (size_t)(bm*128 + arow + p*16)*1024 + k0 + skp, (char*)As + wv*2048 + p*1024);
    gll16(Wb + (size_t)(bn*64 + wrow)*1024 + k0 + skp, (char*)Ws + wv*1024);
    __syncthreads();

    short8 af[4], bf[2];
#pragma unroll
    for (int i = 0; i < 4; i++)
      af[i] = *(const short8*)((const char*)As + (wm*64 + i*16 + m16)*64 + quad*16);
#pragma unroll
    for (int j = 0; j < 2; j++)
      bf[j] = *(const short8*)((const char*)Ws + (wn*32 + j*16 + m16)*64 + quad*16);
#pragma unroll
    for (int i = 0; i < 4; i++)
#pragma unroll
      for (int j = 0; j < 2; j++)
        acc[i][j] = __builtin_amdgcn_mfma_f32_16x16x32_bf16(af[i], bf[j], acc[i][j], 0,0,0);
  }

#pragma unroll
  for (int j = 0; j < 2; j++) {
    const int n_e = bn*64 + wn*32 + j*16 + m16;
    const float bj = bias[n_e];
#pragma unroll
    for (int i = 0; i < 4; i++) {
      const int mbase = bm*128 + wm*64 + i*16 + quad*4;
#pragma unroll
      for (int r = 0; r < 4; r++)
        outF[(size_t)(mbase + r) * 1024 + n_e] = acc[i][j][r] + bj;
    }
  }
}

// ---------------- MFMA flash attention: LDS-free K-loop, single prefetch ----
// K pre-scaled by 0.125*log2e at QKV epilogue: out-of-band p = exp2(st),
// in-band p = exp2(st + log2e). Grid: x = bh (XCD cluster), y = qt.
__global__ __launch_bounds__(256, 3) void attn_k(
    const unsigned short* __restrict__ Qb, const unsigned short* __restrict__ Kf,
    const unsigned short* __restrict__ Vf, const int* __restrict__ wptr,
    unsigned short* __restrict__ ctx)
{
  __shared__ __align__(16) char smem[16896];
  float* Om   = (float*)smem;          // 16 KB epilogue exchange
  float* lbuf = (float*)(smem + 16384);

  const int tid = threadIdx.x, lane = tid & 63, wv = tid >> 6;
  const int wq = wv >> 1, wk = wv & 1;
  const int h = lane >> 5, ln = lane & 31;
  const bool hs = (h == 1);
  const int bh = blockIdx.x, qt = blockIdx.y;
  const int win = *wptr;
  const int q0 = qt * 64 + wq * 32;
  const size_t hb = (size_t)bh * T * HD;

  constexpr float LOG2E = 1.44269504f;

  short8 qf[4];
#pragma unroll
  for (int s = 0; s < 4; s++)
    qf[s] = *(const short8*)(Qb + hb + (size_t)(q0 + ln)*64 + s*16 + h*8);

  short8 onesv;
#pragma unroll
  for (int jj = 0; jj < 8; jj++) onesv[jj] = (short)0x3F80;

  f32x16 O0, O1, Lacc, Zv;
#pragma unroll
  for (int r = 0; r < 16; r++) { O0[r] = 0.f; O1[r] = 0.f; Lacc[r] = 0.f; Zv[r] = 0.f; }
  const int tq = q0 + ln;

  const uint4* kbase = (const uint4*)Kf + (size_t)bh*32*512 + wk*64 + lane;
  const uint4* vbase = (const uint4*)Vf + (size_t)bh*32*512 + wk*64 + lane;

  uint4 kA[4], vA[4];
#pragma unroll
  for (int s = 0; s < 4; s++) kA[s] = kbase[s*128];
#pragma unroll
  for (int u = 0; u < 4; u++) vA[u] = vbase[(u >> 1)*256 + (u & 1)*128];  // u = dt*2+c

  for (int kt = 0; kt < 32; ++kt) {
    // S^T = K·Q^T
    f32x16 st;
#pragma unroll
    for (int s = 0; s < 4; s++) {
      const short8 kf2 = __builtin_bit_cast(short8, kA[s]);
      st = __builtin_amdgcn_mfma_f32_32x32x16_bf16(kf2, qf[s], (s == 0 ? Zv : st), 0, 0, 0);
    }
    // prefetch next K (kA regs free after S) — covered by exp+shfl+PV latency
    if (kt < 31) {
      const size_t o = (size_t)(kt + 1) * 512;
#pragma unroll
      for (int s = 0; s < 4; s++) kA[s] = kbase[o + s*128];
    }

    const int kb = kt*64 + wk*32;
    int sep = 0;
    if (kb > q0 + 31) sep = kb - (q0 + 31);
    else if (q0 > kb + 31) sep = q0 - (kb + 31);
    const int d1 = kb + 31 - q0, d2 = q0 + 31 - kb;
    const int dmax = max(d1 < 0 ? -d1 : d1, d2 < 0 ? -d2 : d2);

    float pr[16];
    if (sep > win) {
#pragma unroll
      for (int r = 0; r < 16; r++) pr[r] = exp2f_(st[r]);
    } else if (dmax <= win) {
#pragma unroll
      for (int r = 0; r < 16; r++) pr[r] = exp2f_(st[r] + LOG2E);
    } else {
      const int tkb = kb + 4*h;
#pragma unroll
      for (int r = 0; r < 16; r++) {
        const int tk = tkb + (r & 3) + 8*(r >> 2);
        int dd = tq - tk; dd = dd < 0 ? -dd : dd;
        pr[r] = exp2f_(st[r] + (dd <= win ? LOG2E : 0.0f));
      }
    }

    unsigned pk[8];
#pragma unroll
    for (int g = 0; g < 8; g++)
      pk[g] = __builtin_amdgcn_perm(__builtin_bit_cast(unsigned, pr[2*g+1]),
                                    __builtin_bit_cast(unsigned, pr[2*g]),
                                    0x07060302u);

#pragma unroll
    for (int c = 0; c < 2; c++) {
      const unsigned sh0 = (unsigned)__shfl_xor((int)pk[4*c+0], 32, 64);
      const unsigned sh1 = (unsigned)__shfl_xor((int)pk[4*c+1], 32, 64);
      const unsigned sh2 = (unsigned)__shfl_xor((int)pk[4*c+2], 32, 64);
      const unsigned sh3 = (unsigned)__shfl_xor((int)pk[4*c+3], 32, 64);
      union { unsigned u[4]; short8 v; } P;
      P.u[0] = hs ? sh2 : pk[4*c+0];
      P.u[1] = hs ? sh3 : pk[4*c+1];
      P.u[2] = hs ? pk[4*c+2] : sh0;
      P.u[3] = hs ? pk[4*c+3] : sh1;
#pragma unroll
      for (int dt = 0; dt < 2; dt++) {
        const short8 vf2 = __builtin_bit_cast(short8, vA[dt*2 + c]);
        if (dt == 0) O0 = __builtin_amdgcn_mfma_f32_32x32x16_bf16(P.v, vf2, O0, 0,0,0);
        else         O1 = __builtin_amdgcn_mfma_f32_32x32x16_bf16(P.v, vf2, O1, 0,0,0);
      }
      Lacc = __builtin_amdgcn_mfma_f32_32x32x16_bf16(P.v, onesv, Lacc, 0,0,0);
    }

    // prefetch next V (vA free after PV) — covered by next S+exp latency
    if (kt < 31) {
      const size_t o = (size_t)(kt + 1) * 512;
#pragma unroll
      for (int u = 0; u < 4; u++) vA[u] = vbase[o + (u >> 1)*256 + (u & 1)*128];
    }
  }

  __syncthreads();
  if (wk == 1) {
#pragma unroll
    for (int r = 0; r < 16; r++) {
      Om[wq*2048 + r*64 + lane]        = O0[r];
      Om[wq*2048 + (16 + r)*64 + lane] = O1[r];
    }
    if (ln == 0) {
#pragma unroll
      for (int r = 0; r < 16; r++)
        lbuf[wq*32 + (r & 3) + 8*(r >> 2) + 4*h] = Lacc[r];
    }
  }
  __syncthreads();
  if (wk == 0) {
    const int b = bh >> 4, hh = bh & 15;
#pragma unroll
    for (int r = 0; r < 16; r++) {
      const int qrow = (r & 3) + 8*(r >> 2) + 4*h;
      const float lt = Lacc[r] + lbuf[wq*32 + qrow];
      const float linv = 1.0f / lt;
      const int t = q0 + qrow;
      const float o0 = (O0[r] + Om[wq*2048 + r*64 + lane]) * linv;
      const float o1 = (O1[r] + Om[wq*2048 + (16 + r)*64 + lane]) * linv;
      unsigned short* cp = ctx + (size_t)(b*2048 + t)*1024 + hh*64;
      cp[ln]      = (unsigned short)bf16rne(o0);
      cp[32 + ln] = (unsigned short)bf16rne(o1);
    }
  }
}

// ---------------- launch ----------------
extern "C" void kernel_launch(void* const* d_in, const int* in_sizes, int n_in,
                              void* d_out, int out_size, void* d_ws, size_t ws_size,
                              hipStream_t stream)
{
  const float* query = (const float*)d_in[0];
  const float* key   = (const float*)d_in[1];
  const float* value = (const float*)d_in[2];
  const float* ipw   = (const float*)d_in[3];
  const float* ipb   = (const float*)d_in[4];
  const float* opw   = (const float*)d_in[5];
  const float* opb   = (const float*)d_in[6];
  const int*   win   = (const int*)d_in[7];

  char* ws = (char*)d_ws;
  unsigned short* Winbf  = (unsigned short*)(ws);             // 3072*1024
  unsigned short* Woutbf = (unsigned short*)(ws + 6291456);   // 1024*1024
  unsigned short* Qin    = (unsigned short*)(ws + 8388608);   // [4096,1024] bf16
  unsigned short* Kin    = (unsigned short*)(ws + 16777216);
  unsigned short* Vin    = (unsigned short*)(ws + 25165824);
  unsigned short* Qb     = (unsigned short*)(ws + 33554432);  // [b,h,t,d]
  unsigned short* Kf     = (unsigned short*)(ws + 41943040);  // fragment-major, pre-scaled
  unsigned short* Vf     = (unsigned short*)(ws + 50331648);  // fragment-major
  unsigned short* ctx    = (unsigned short*)(ws + 58720256);  // [4096][1024]

  convert_k<<<16384, 256, 0, stream>>>(ipw, opw, query, key, value, (unsigned*)ws);

  gemm_qkv<<<dim3(24, 32), 256, 0, stream>>>(
      Qin, Kin, Vin, Winbf, ipb, Qb, Kf, Vf);

  attn_k<<<dim3(32, 32), 256, 0, stream>>>(Qb, Kf, Vf, win, ctx);

  gemm_out<<<dim3(16, 32), 256, 0, stream>>>(
      ctx, Woutbf, opb, (float*)d_out);
}